// Round 1
// baseline (590.041 us; speedup 1.0000x reference)
//
#include <hip/hip_runtime.h>
#include <stdint.h>

// Problem constants (fixed by reference): T=512, B=256, H=256, 3H=768.
// Pipeline:
//   prep_weights: Wi -> WiT (bf16 [768][256], B^T for gi_gemm);
//                 Wh -> WhFrag (bf16, per-wave MFMA-fragment-major for gru_scan).
//   gi_gemm:      GI[b][t][0:768] = bf16(ins[t][b]@Wi + bi). Standard 128x128 tile,
//                 BK=64, 4 waves, reg-staged dbuf, padded LDS (stride 72 -> 2-way free).
//   gru_scan:     reset-segment-parallel scan, 256 wgs (1/batch), 16 slots/wg.
//                 Wh residency is explicit: r/z gates = 32 frags in VGPRs (128 regs),
//                 n gate = 16 frags in LDS (128 KB, conflict-free fragment-major).
//                 Per-slot [start,end] precomputed -> GI rows are consecutive ->
//                 per-lane direct GI loads prefetched one full iteration ahead.
// MFMA 16x16x32 bf16 layouts (HW-verified):
//   A[m=lane&15][k=quad*8+j], B[k=quad*8+j][n=lane&15], C/D[row=quad*4+reg][col=lane&15]

typedef __attribute__((ext_vector_type(8))) __bf16 bf16x8;
typedef __attribute__((ext_vector_type(4))) float f32x4;

__device__ __forceinline__ float bf2f(unsigned short u) {
    union { unsigned int i; float f; } v; v.i = ((unsigned int)u) << 16; return v.f;
}
__device__ __forceinline__ unsigned short f2bf(float f) {
    union { float f; unsigned int i; } v; v.f = f;
    unsigned int x = v.i;
    x = x + 0x7fffu + ((x >> 16) & 1u);   // RNE
    return (unsigned short)(x >> 16);
}
__device__ __forceinline__ float fsig(float x) {
    return __builtin_amdgcn_rcpf(1.f + __builtin_amdgcn_exp2f(-1.442695041f * x));
}
__device__ __forceinline__ float ftanh(float x) {
    return 1.f - 2.f * __builtin_amdgcn_rcpf(1.f + __builtin_amdgcn_exp2f(2.885390082f * x));
}

// ---------------------------------------------------------------- prep
// y==0: WiT[c][k] = Wi[k][c]  (B^T layout for gi_gemm)
// y==1: WhFrag flat idx = ((wv*48 + f)*64 + lane)*8 + j, f = g2*8+kt, g2 = g*2+tl:
//       value = Wh[kt*32+quad*8+j][g*256 + wv*32 + tl*16 + n16]
__global__ void prep_weights(const float* __restrict__ Wi, const float* __restrict__ Wh,
                             unsigned short* __restrict__ WiT, unsigned short* __restrict__ WhFrag) {
    const int idx = blockIdx.x * 256 + threadIdx.x;          // [0, 196608)
    if (blockIdx.y == 0) {
        const int c = idx >> 8, k = idx & 255;
        WiT[c * 256 + k] = f2bf(Wi[k * 768 + c]);
    } else {
        const int j    = idx & 7;
        const int lane = (idx >> 3) & 63;
        const int fi   = (idx >> 9) % 48;
        const int wv   = (idx >> 9) / 48;
        const int kt = fi & 7, g2 = fi >> 3;
        const int g = g2 >> 1, tl = g2 & 1;
        const int quad = lane >> 4, n16 = lane & 15;
        const int k = kt * 32 + quad * 8 + j;
        const int c = g * 256 + wv * 32 + tl * 16 + n16;
        WhFrag[idx] = f2bf(Wh[k * 768 + c]);
    }
}

// ---------------------------------------------------------------- kernel 1: GI = ins@Wi + bi
// M=131072 (rows t*256+b), N=768, K=256. BM=BN=128, BK=64. 4 waves (wm x wn = 2x2),
// each wave owns 64x64 via 4x4 fragments of 16x16.
__launch_bounds__(256, 2)
__global__ void gi_gemm(const float* __restrict__ ins, const unsigned short* __restrict__ WiT,
                        const float* __restrict__ bi, unsigned short* __restrict__ GI) {
    __shared__ char smem[36864];
    unsigned short* a_t = (unsigned short*)smem;            // [128][72] bf16
    unsigned short* b_t = a_t + 128 * 72;                   // [128][72] bf16
    float* stg = (float*)smem;                              // [64][132] f32, aliases tiles in epilogue

    const int bid0 = blockIdx.x;
    const int bid  = (bid0 & 7) * 768 + (bid0 >> 3);        // bijective XCD swizzle (6144 = 8*768)
    const int mtile = bid / 6, ntile = bid - mtile * 6;
    const int R0 = mtile * 128;                             // global row base (row = t*256+b)
    const int N0 = ntile * 128;
    const int tid = threadIdx.x;
    const int lane = tid & 63;
    const int wv = tid >> 6;
    const int quad = lane >> 4, n16 = lane & 15;
    const int wm = wv >> 1, wn = wv & 1;

    const int srow = tid >> 1;                              // staging row 0..127
    const int koff = (tid & 1) * 32;                        // element offset within 64-wide K slice

    float bi_r[4];
#pragma unroll
    for (int nt = 0; nt < 4; ++nt) bi_r[nt] = bi[N0 + wn * 64 + nt * 16 + n16];

    // prefetch K-step 0
    float4 areg[8];
    uint4 breg[4];
    {
        const float* ap = ins + (size_t)(R0 + srow) * 256 + koff;
#pragma unroll
        for (int i = 0; i < 8; ++i) areg[i] = *(const float4*)(ap + i * 4);
        const unsigned short* bp = WiT + (size_t)(N0 + srow) * 256 + koff;
#pragma unroll
        for (int i = 0; i < 4; ++i) breg[i] = *(const uint4*)(bp + i * 8);
    }

    f32x4 acc[4][4] = {};

    for (int kk = 0; kk < 4; ++kk) {
        __syncthreads();   // previous compute phase done reading tiles
        // stage prefetched regs -> LDS (A: fp32->bf16 convert)
#pragma unroll
        for (int i = 0; i < 4; ++i) {
            bf16x8 av;
            const float* f = (const float*)&areg[i * 2];
#pragma unroll
            for (int j2 = 0; j2 < 8; ++j2) av[j2] = (__bf16)f[j2];
            *(bf16x8*)(&a_t[srow * 72 + koff + i * 8]) = av;
        }
#pragma unroll
        for (int i = 0; i < 4; ++i)
            *(uint4*)(&b_t[srow * 72 + koff + i * 8]) = breg[i];
        __syncthreads();
        if (kk < 3) {   // prefetch next K-step while computing
            const float* ap = ins + (size_t)(R0 + srow) * 256 + (kk + 1) * 64 + koff;
#pragma unroll
            for (int i = 0; i < 8; ++i) areg[i] = *(const float4*)(ap + i * 4);
            const unsigned short* bp = WiT + (size_t)(N0 + srow) * 256 + (kk + 1) * 64 + koff;
#pragma unroll
            for (int i = 0; i < 4; ++i) breg[i] = *(const uint4*)(bp + i * 8);
        }
#pragma unroll
        for (int kt = 0; kt < 2; ++kt) {
            bf16x8 afr[4], bfr[4];
#pragma unroll
            for (int mt = 0; mt < 4; ++mt)
                afr[mt] = *(const bf16x8*)(&a_t[(wm * 64 + mt * 16 + n16) * 72 + kt * 32 + quad * 8]);
#pragma unroll
            for (int nt = 0; nt < 4; ++nt)
                bfr[nt] = *(const bf16x8*)(&b_t[(wn * 64 + nt * 16 + n16) * 72 + kt * 32 + quad * 8]);
#pragma unroll
            for (int mt = 0; mt < 4; ++mt)
#pragma unroll
                for (int nt = 0; nt < 4; ++nt)
                    acc[mt][nt] = __builtin_amdgcn_mfma_f32_16x16x32_bf16(afr[mt], bfr[nt], acc[mt][nt], 0, 0, 0);
        }
    }

    // epilogue: two 64-row half-passes through LDS for coalesced bf16 stores
#pragma unroll
    for (int p = 0; p < 2; ++p) {
        __syncthreads();   // tiles (or previous stg pass) dead
        if (wm == p) {
#pragma unroll
            for (int mt = 0; mt < 4; ++mt)
#pragma unroll
                for (int nt = 0; nt < 4; ++nt)
#pragma unroll
                    for (int r = 0; r < 4; ++r)
                        stg[(mt * 16 + quad * 4 + r) * 132 + wn * 64 + nt * 16 + n16] = acc[mt][nt][r] + bi_r[nt];
        }
        __syncthreads();
        const int row = tid >> 2, c0 = (tid & 3) * 32;
        const int grow = R0 + p * 64 + row;
        const int tg = grow >> 8, bg = grow & 255;
        unsigned short* dst = GI + ((size_t)bg * 512 + tg) * 768 + N0 + c0;   // b-major GI
        const float* sp = &stg[row * 132 + c0];
#pragma unroll
        for (int u = 0; u < 4; ++u) {
            bf16x8 o;
#pragma unroll
            for (int j2 = 0; j2 < 8; ++j2) o[j2] = (__bf16)sp[u * 8 + j2];
            *(bf16x8*)(dst + u * 8) = o;
        }
    }
}

// ---------------------------------------------------------------- kernel 2: segment-parallel GRU scan
// slot = quad*4+r owns window [slot*32, slot*32+32): processes rows [start, end]
// consecutively (start = first reset in window, end = first reset >= next window - 1).

#define SCAN_STEP(GCUR, GNXT)                                                                   \
    {                                                                                           \
        const bool any_ = (t_cur[0] <= t_end[0]) | (t_cur[1] <= t_end[1]) |                     \
                          (t_cur[2] <= t_end[2]) | (t_cur[3] <= t_end[3]);                      \
        if (__ballot((int)any_) == 0ull) break;                                                 \
        __syncthreads();                                                                        \
        f32x4 acc2[6] = {};                                                                     \
        _Pragma("unroll")                                                                       \
        for (int kt = 0; kt < 8; ++kt) {                                                        \
            bf16x8 af = *(const bf16x8*)(&s_h[buf][n16 * 264 + kt * 32 + quad * 8]);            \
            _Pragma("unroll")                                                                   \
            for (int g2 = 0; g2 < 4; ++g2)                                                      \
                acc2[g2] = __builtin_amdgcn_mfma_f32_16x16x32_bf16(af, wfr[g2][kt], acc2[g2], 0, 0, 0); \
            _Pragma("unroll")                                                                   \
            for (int tl = 0; tl < 2; ++tl) {                                                    \
                bf16x8 bfn = *(const bf16x8*)(&s_whn[(wv * 16 + tl * 8 + kt) * 512 + lane * 8]); \
                acc2[4 + tl] = __builtin_amdgcn_mfma_f32_16x16x32_bf16(af, bfn, acc2[4 + tl], 0, 0, 0); \
            }                                                                                   \
        }                                                                                       \
        _Pragma("unroll")                                                                       \
        for (int r = 0; r < 4; ++r) {                                                           \
            const int trn = (t_cur[r] < t_end[r]) ? (t_cur[r] + 1) : 0;                         \
            const unsigned short* gp = GI + gibase + (size_t)trn * 768;                         \
            GNXT[r][0] = gp[0];   GNXT[r][1] = gp[16];                                          \
            GNXT[r][2] = gp[256]; GNXT[r][3] = gp[272];                                         \
            GNXT[r][4] = gp[512]; GNXT[r][5] = gp[528];                                         \
        }                                                                                       \
        float hn[2][4];                                                                         \
        _Pragma("unroll")                                                                       \
        for (int r = 0; r < 4; ++r) {                                                           \
            const bool alive = t_cur[r] <= t_end[r];                                            \
            _Pragma("unroll")                                                                   \
            for (int tl = 0; tl < 2; ++tl) {                                                    \
                const int c = wv * 32 + tl * 16 + n16;                                          \
                const float gr = bf2f(GCUR[r][tl]);                                             \
                const float gz = bf2f(GCUR[r][2 + tl]);                                         \
                const float gn = bf2f(GCUR[r][4 + tl]);                                         \
                const float rr = fsig(gr + acc2[tl][r]);                                        \
                const float zz = fsig(gz + acc2[2 + tl][r]);                                    \
                const float nn = ftanh(gn + rr * (acc2[4 + tl][r] + bhn_r[tl]));                \
                hn[tl][r] = (1.f - zz) * nn + zz * h_prev[tl][r];                               \
                if (alive) out[((size_t)t_cur[r] * 256 + b) * 256 + c] = hn[tl][r];             \
            }                                                                                   \
        }                                                                                       \
        _Pragma("unroll")                                                                       \
        for (int r = 0; r < 4; ++r) {                                                           \
            const int slot = quad * 4 + r;                                                      \
            const bool alive = t_cur[r] <= t_end[r];                                            \
            const int tn = t_cur[r] + 1;                                                        \
            const bool nalive = alive && (tn <= t_end[r]);                                      \
            float k0 = 0.f, k1 = 0.f;                                                           \
            if (nalive && s_reset[tn] == 0) { k0 = hn[0][r]; k1 = hn[1][r]; }                   \
            h_prev[0][r] = k0; h_prev[1][r] = k1;                                               \
            s_h[buf ^ 1][slot * 264 + wv * 32 + n16] = f2bf(k0);                                \
            s_h[buf ^ 1][slot * 264 + wv * 32 + 16 + n16] = f2bf(k1);                           \
            if (alive) t_cur[r] = tn;                                                           \
        }                                                                                       \
        buf ^= 1;                                                                               \
    }

__launch_bounds__(512, 2)
__global__ void gru_scan(const unsigned short* __restrict__ GI, const int* __restrict__ resets,
                         const float* __restrict__ carry, const unsigned short* __restrict__ WhFrag,
                         const float* __restrict__ bhn, float* __restrict__ out) {
    __shared__ int s_reset[512];                         //   2,048 B
    __shared__ unsigned short s_h[2][16 * 264];          //  16,896 B (h bf16, A-operand, dbuf)
    __shared__ unsigned short s_whn[8 * 16 * 512];       // 131,072 B (n-gate Wh frags, per-wave)

    const int b = blockIdx.x;
    const int tid = threadIdx.x;
    const int lane = tid & 63, wv = tid >> 6;
    const int quad = lane >> 4, n16 = lane & 15;

    s_reset[tid] = resets[tid * 256 + b];

    // Wh fragments: r,z gates resident in VGPRs (32 frags = 128 regs); n gate -> LDS.
    const unsigned short* wfbase = WhFrag + (size_t)wv * 48 * 512 + lane * 8;
    bf16x8 wfr[4][8];
#pragma unroll
    for (int g2 = 0; g2 < 4; ++g2)
#pragma unroll
        for (int kt = 0; kt < 8; ++kt)
            wfr[g2][kt] = *(const bf16x8*)(wfbase + (g2 * 8 + kt) * 512);
#pragma unroll
    for (int j2 = 0; j2 < 16; ++j2) {
        bf16x8 v = *(const bf16x8*)(wfbase + (32 + j2) * 512);
        *(bf16x8*)(&s_whn[(wv * 16 + j2) * 512 + lane * 8]) = v;
    }
    float bhn_r[2];
    bhn_r[0] = bhn[wv * 32 + n16];
    bhn_r[1] = bhn[wv * 32 + 16 + n16];

    __syncthreads();   // s_reset visible to all

    // per-slot [start, end] from the reset pattern
    int t_cur[4], t_end[4];
    float h_prev[2][4];
#pragma unroll
    for (int r = 0; r < 4; ++r) {
        const int slot = quad * 4 + r;
        const int w0 = slot * 32;
        int st = -1;
        for (int t = w0; t < w0 + 32; ++t)
            if (t == 0 || s_reset[t] != 0) { st = t; break; }
        int en = 511;
        for (int t = w0 + 32; t < 512; ++t)
            if (s_reset[t] != 0) { en = t - 1; break; }
        float h0 = 0.f, h1 = 0.f;
        if (st == 0 && s_reset[0] == 0) {   // faithful: initial carry when t=0 not reset
            h0 = carry[b * 256 + wv * 32 + n16];
            h1 = carry[b * 256 + wv * 32 + 16 + n16];
        }
        if (st < 0) { t_cur[r] = 1; t_end[r] = 0; }   // dead slot (no segment starts here)
        else        { t_cur[r] = st; t_end[r] = en; }
        h_prev[0][r] = h0; h_prev[1][r] = h1;
        s_h[0][slot * 264 + wv * 32 + n16] = f2bf(h0);
        s_h[0][slot * 264 + wv * 32 + 16 + n16] = f2bf(h1);
    }

    // GI prefetch for iteration 0 (per-lane direct loads; lanes n16-contiguous)
    const size_t gibase = (size_t)b * 512 * 768 + (size_t)(wv * 32 + n16);
    unsigned short gva[4][6], gvb[4][6];
#pragma unroll
    for (int r = 0; r < 4; ++r) {
        const int tr0 = (t_cur[r] <= t_end[r]) ? t_cur[r] : 0;
        const unsigned short* gp = GI + gibase + (size_t)tr0 * 768;
        gva[r][0] = gp[0];   gva[r][1] = gp[16];
        gva[r][2] = gp[256]; gva[r][3] = gp[272];
        gva[r][4] = gp[512]; gva[r][5] = gp[528];
    }

    int buf = 0;
    for (int it2 = 0; it2 < 256; ++it2) {
        SCAN_STEP(gva, gvb)
        SCAN_STEP(gvb, gva)
    }
}

// ---------------------------------------------------------------- launch
extern "C" void kernel_launch(void* const* d_in, const int* in_sizes, int n_in,
                              void* d_out, int out_size, void* d_ws, size_t ws_size,
                              hipStream_t stream) {
    const float* ins   = (const float*)d_in[0];
    const int* resets  = (const int*)d_in[1];
    const float* carry = (const float*)d_in[2];
    const float* Wi    = (const float*)d_in[3];
    const float* bi    = (const float*)d_in[4];
    const float* Wh    = (const float*)d_in[5];
    const float* bhn   = (const float*)d_in[6];
    float* out = (float*)d_out;

    unsigned short* WiT    = (unsigned short*)d_ws;     // [768][256] bf16
    unsigned short* WhFrag = WiT + 196608;              // [8][48][64][8] bf16 fragment-major
    unsigned short* GI     = WhFrag + 196608;           // [256][512][768] bf16 (b-major)

    prep_weights<<<dim3(768, 2), dim3(256), 0, stream>>>(Wi, Wh, WiT, WhFrag);
    gi_gemm<<<dim3(6144), dim3(256), 0, stream>>>(ins, WiT, bi, GI);
    gru_scan<<<dim3(256), dim3(512), 0, stream>>>(GI, resets, carry, WhFrag, bhn, out);
}

// Round 2
// 571.493 us; speedup vs baseline: 1.0325x; 1.0325x over previous
//
#include <hip/hip_runtime.h>
#include <stdint.h>

// Problem constants (fixed by reference): T=512, B=256, H=256, 3H=768.
// Pipeline:
//   prep_weights: Wi -> WiT (bf16 [768][256], B^T for gi_gemm);
//                 Wh -> WhFrag (bf16, per-wave MFMA-fragment-major for gru_scan).
//   gi_gemm:      GI[b][t][perm(768)] = bf16(ins[t][b]@Wi + bi).
//                 M is B-MAJOR: r = b*512 + t -> GI writes are 128 consecutive
//                 1536-B rows per tile (no L2 set aliasing; round-1's t-major
//                 tiles wrote 256-B chunks at 768-KB stride = all one L2 set,
//                 2.5x write amplification). 128x128 tile, BK=64, 4 waves,
//                 granule XOR-swizzled LDS (round-1 pad was an 8-way ds_write
//                 conflict: 8 rows x 36 dwords = 0 mod 32).
//   gru_scan:     reset-segment-parallel scan, 256 wgs (1/batch), 16 slots/wg.
//                 Wh: r/z gates in VGPRs (32 frags = 128 regs), n gate in LDS.
//                 GI permuted so each lane's gate pair (c, c+16) is one uint:
//                 12 x 4-B loads per prefetch (was 24 x 2-B) -> 24 regs/buffer.
// GI permutation (within each 256-col gate block g): col cg -> pos
//   li = (cg>>5)*16 + (cg&15), w = (cg>>4)&1, pos = g*256 + li*2 + w.
//   Lane (wv,n16) reads uint at 32-bit index g*128 + wv*16 + n16 ->
//   {lo = col wv*32+n16 (tl=0), hi = col wv*32+16+n16 (tl=1)}.
// MFMA 16x16x32 bf16 layouts (HW-verified):
//   A[m=lane&15][k=quad*8+j], B[k=quad*8+j][n=lane&15], C/D[row=quad*4+reg][col=lane&15]

typedef __attribute__((ext_vector_type(8))) __bf16 bf16x8;
typedef __attribute__((ext_vector_type(4))) float f32x4;

__device__ __forceinline__ float bf2f(unsigned short u) {
    union { unsigned int i; float f; } v; v.i = ((unsigned int)u) << 16; return v.f;
}
__device__ __forceinline__ unsigned short f2bf(float f) {
    union { float f; unsigned int i; } v; v.f = f;
    unsigned int x = v.i;
    x = x + 0x7fffu + ((x >> 16) & 1u);   // RNE
    return (unsigned short)(x >> 16);
}
__device__ __forceinline__ float fsig(float x) {
    return __builtin_amdgcn_rcpf(1.f + __builtin_amdgcn_exp2f(-1.442695041f * x));
}
__device__ __forceinline__ float ftanh(float x) {
    return 1.f - 2.f * __builtin_amdgcn_rcpf(1.f + __builtin_amdgcn_exp2f(2.885390082f * x));
}

// ---------------------------------------------------------------- prep
// y==0: WiT[c][k] = Wi[k][c]  (B^T layout for gi_gemm)
// y==1: WhFrag flat idx = ((wv*48 + f)*64 + lane)*8 + j, f = g2*8+kt, g2 = g*2+tl:
//       value = Wh[kt*32+quad*8+j][g*256 + wv*32 + tl*16 + n16]
__global__ void prep_weights(const float* __restrict__ Wi, const float* __restrict__ Wh,
                             unsigned short* __restrict__ WiT, unsigned short* __restrict__ WhFrag) {
    const int idx = blockIdx.x * 256 + threadIdx.x;          // [0, 196608)
    if (blockIdx.y == 0) {
        const int c = idx >> 8, k = idx & 255;
        WiT[c * 256 + k] = f2bf(Wi[k * 768 + c]);
    } else {
        const int j    = idx & 7;
        const int lane = (idx >> 3) & 63;
        const int fi   = (idx >> 9) % 48;
        const int wv   = (idx >> 9) / 48;
        const int kt = fi & 7, g2 = fi >> 3;
        const int g = g2 >> 1, tl = g2 & 1;
        const int quad = lane >> 4, n16 = lane & 15;
        const int k = kt * 32 + quad * 8 + j;
        const int c = g * 256 + wv * 32 + tl * 16 + n16;
        WhFrag[idx] = f2bf(Wh[k * 768 + c]);
    }
}

// ---------------------------------------------------------------- kernel 1: GI = ins@Wi + bi
// M=131072 b-major rows (r = b*512+t), N=768, K=256. BM=BN=128, BK=64.
// 4 waves (wm x wn = 2x2), each wave 64x64 via 4x4 fragments of 16x16.
__launch_bounds__(256, 2)
__global__ void gi_gemm(const float* __restrict__ ins, const unsigned short* __restrict__ WiT,
                        const float* __restrict__ bi, unsigned short* __restrict__ GI) {
    __shared__ char smem[36864];
    unsigned short* a_t = (unsigned short*)smem;            // [128][64] bf16, granule-swizzled
    unsigned short* b_t = a_t + 128 * 64;                   // [128][64] bf16, granule-swizzled
    float* stg = (float*)smem;                              // [64][132] f32, aliases tiles in epilogue

    const int bid0 = blockIdx.x;
    const int bid  = (bid0 & 7) * 768 + (bid0 >> 3);        // bijective XCD swizzle (6144 = 8*768)
    const int mtile = bid / 6, ntile = bid - mtile * 6;     // siblings (same mtile) share XCD+time
    const int R0 = mtile * 128;                             // b-major row base: b = R0>>9, t0 = R0&511
    const int bb = R0 >> 9, t0 = R0 & 511;
    const int N0 = ntile * 128;
    const int tid = threadIdx.x;
    const int lane = tid & 63;
    const int wv = tid >> 6;
    const int quad = lane >> 4, n16 = lane & 15;
    const int wm = wv >> 1, wn = wv & 1;

    const int srow = tid >> 1;                              // staging row 0..127
    const int koff = (tid & 1) * 32;                        // element offset within 64-wide K slice
    const int gb = koff >> 3;                               // granule base (0 or 4)
    const int sw = srow & 7;                                // granule swizzle key

    float bi_r[4];
#pragma unroll
    for (int nt = 0; nt < 4; ++nt) bi_r[nt] = bi[N0 + wn * 64 + nt * 16 + n16];

    // prefetch K-step 0 (A row = ins[t0+srow][bb][:], stride 256 KB between rows)
    float4 areg[8];
    uint4 breg[4];
    {
        const float* ap = ins + ((size_t)(t0 + srow) * 256 + bb) * 256 + koff;
#pragma unroll
        for (int i = 0; i < 8; ++i) areg[i] = *(const float4*)(ap + i * 4);
        const unsigned short* bp = WiT + (size_t)(N0 + srow) * 256 + koff;
#pragma unroll
        for (int i = 0; i < 4; ++i) breg[i] = *(const uint4*)(bp + i * 8);
    }

    f32x4 acc[4][4] = {};

    for (int kk = 0; kk < 4; ++kk) {
        __syncthreads();   // previous compute phase done reading tiles
        // stage prefetched regs -> LDS (A: fp32->bf16), granule-XOR-swizzled
#pragma unroll
        for (int i = 0; i < 4; ++i) {
            bf16x8 av;
            const float* f = (const float*)&areg[i * 2];
#pragma unroll
            for (int j2 = 0; j2 < 8; ++j2) av[j2] = (__bf16)f[j2];
            *(bf16x8*)(&a_t[srow * 64 + ((gb + i) ^ sw) * 8]) = av;
        }
#pragma unroll
        for (int i = 0; i < 4; ++i)
            *(uint4*)(&b_t[srow * 64 + ((gb + i) ^ sw) * 8]) = breg[i];
        __syncthreads();
        if (kk < 3) {   // prefetch next K-step while computing
            const float* ap = ins + ((size_t)(t0 + srow) * 256 + bb) * 256 + (kk + 1) * 64 + koff;
#pragma unroll
            for (int i = 0; i < 8; ++i) areg[i] = *(const float4*)(ap + i * 4);
            const unsigned short* bp = WiT + (size_t)(N0 + srow) * 256 + (kk + 1) * 64 + koff;
#pragma unroll
            for (int i = 0; i < 4; ++i) breg[i] = *(const uint4*)(bp + i * 8);
        }
#pragma unroll
        for (int kt = 0; kt < 2; ++kt) {
            bf16x8 afr[4], bfr[4];
#pragma unroll
            for (int mt = 0; mt < 4; ++mt)
                afr[mt] = *(const bf16x8*)(&a_t[(wm * 64 + mt * 16 + n16) * 64 + ((kt * 4 + quad) ^ (n16 & 7)) * 8]);
#pragma unroll
            for (int nt = 0; nt < 4; ++nt)
                bfr[nt] = *(const bf16x8*)(&b_t[(wn * 64 + nt * 16 + n16) * 64 + ((kt * 4 + quad) ^ (n16 & 7)) * 8]);
#pragma unroll
            for (int mt = 0; mt < 4; ++mt)
#pragma unroll
                for (int nt = 0; nt < 4; ++nt)
                    acc[mt][nt] = __builtin_amdgcn_mfma_f32_16x16x32_bf16(afr[mt], bfr[nt], acc[mt][nt], 0, 0, 0);
        }
    }

    // epilogue: two 64-row half-passes through LDS; scatter applies the GI
    // permutation pi(c) = (c>>5)*32 + (c&15)*2 + ((c>>4)&1) (within-tile bijection),
    // so the store side stays contiguous.
#pragma unroll
    for (int p = 0; p < 2; ++p) {
        __syncthreads();   // tiles (or previous stg pass) dead
        if (wm == p) {
#pragma unroll
            for (int mt = 0; mt < 4; ++mt)
#pragma unroll
                for (int nt = 0; nt < 4; ++nt) {
                    const int c = wn * 64 + nt * 16 + n16;
                    const int pc = ((c >> 5) << 5) + ((c & 15) << 1) + ((c >> 4) & 1);
#pragma unroll
                    for (int r = 0; r < 4; ++r)
                        stg[(mt * 16 + quad * 4 + r) * 132 + pc] = acc[mt][nt][r] + bi_r[nt];
                }
        }
        __syncthreads();
        const int row = tid >> 2, c0 = (tid & 3) * 32;
        const int grow = R0 + p * 64 + row;                 // b-major: consecutive GI rows
        unsigned short* dst = GI + (size_t)grow * 768 + N0 + c0;
        const float* sp = &stg[row * 132 + c0];
#pragma unroll
        for (int u = 0; u < 4; ++u) {
            bf16x8 o;
#pragma unroll
            for (int j2 = 0; j2 < 8; ++j2) o[j2] = (__bf16)sp[u * 8 + j2];
            *(bf16x8*)(dst + u * 8) = o;
        }
    }
}

// ---------------------------------------------------------------- kernel 2: segment-parallel GRU scan
// slot = quad*4+r owns window [slot*32, slot*32+32): processes rows [start, end]
// consecutively. GI prefetched one full iteration ahead as 12 packed uints.

#define SCAN_STEP(GCUR, GNXT)                                                                   \
    {                                                                                           \
        const bool any_ = (t_cur[0] <= t_end[0]) | (t_cur[1] <= t_end[1]) |                     \
                          (t_cur[2] <= t_end[2]) | (t_cur[3] <= t_end[3]);                      \
        if (__ballot((int)any_) == 0ull) break;                                                 \
        __syncthreads();                                                                        \
        f32x4 acc2[6] = {};                                                                     \
        _Pragma("unroll")                                                                       \
        for (int kt = 0; kt < 8; ++kt) {                                                        \
            bf16x8 af = *(const bf16x8*)(&s_h[buf][n16 * 264 + kt * 32 + quad * 8]);            \
            _Pragma("unroll")                                                                   \
            for (int g2 = 0; g2 < 4; ++g2)                                                      \
                acc2[g2] = __builtin_amdgcn_mfma_f32_16x16x32_bf16(af, wfr[g2][kt], acc2[g2], 0, 0, 0); \
            _Pragma("unroll")                                                                   \
            for (int tl = 0; tl < 2; ++tl) {                                                    \
                bf16x8 bfn = *(const bf16x8*)(&s_whn[(wv * 16 + tl * 8 + kt) * 512 + lane * 8]); \
                acc2[4 + tl] = __builtin_amdgcn_mfma_f32_16x16x32_bf16(af, bfn, acc2[4 + tl], 0, 0, 0); \
            }                                                                                   \
        }                                                                                       \
        _Pragma("unroll")                                                                       \
        for (int r = 0; r < 4; ++r) {                                                           \
            const int trn = (t_cur[r] < t_end[r]) ? (t_cur[r] + 1) : 0;                         \
            const unsigned int* gp = GI32 + (size_t)trn * 384 + gcol;                           \
            GNXT[r][0] = gp[0]; GNXT[r][1] = gp[128]; GNXT[r][2] = gp[256];                     \
        }                                                                                       \
        float hn[2][4];                                                                         \
        _Pragma("unroll")                                                                       \
        for (int r = 0; r < 4; ++r) {                                                           \
            const bool alive = t_cur[r] <= t_end[r];                                            \
            const unsigned int ur = GCUR[r][0], uz = GCUR[r][1], un = GCUR[r][2];               \
            _Pragma("unroll")                                                                   \
            for (int tl = 0; tl < 2; ++tl) {                                                    \
                const int c = wv * 32 + tl * 16 + n16;                                          \
                const float gr = bf2f((unsigned short)(tl ? (ur >> 16) : (ur & 0xffffu)));      \
                const float gz = bf2f((unsigned short)(tl ? (uz >> 16) : (uz & 0xffffu)));      \
                const float gn = bf2f((unsigned short)(tl ? (un >> 16) : (un & 0xffffu)));      \
                const float rr = fsig(gr + acc2[tl][r]);                                        \
                const float zz = fsig(gz + acc2[2 + tl][r]);                                    \
                const float nn = ftanh(gn + rr * (acc2[4 + tl][r] + bhn_r[tl]));                \
                hn[tl][r] = (1.f - zz) * nn + zz * h_prev[tl][r];                               \
                if (alive) out[((size_t)t_cur[r] * 256 + b) * 256 + c] = hn[tl][r];             \
            }                                                                                   \
        }                                                                                       \
        _Pragma("unroll")                                                                       \
        for (int r = 0; r < 4; ++r) {                                                           \
            const int slot = quad * 4 + r;                                                      \
            const bool alive = t_cur[r] <= t_end[r];                                            \
            const int tn = t_cur[r] + 1;                                                        \
            const bool nalive = alive && (tn <= t_end[r]);                                      \
            float k0 = 0.f, k1 = 0.f;                                                           \
            if (nalive && s_reset[tn] == 0) { k0 = hn[0][r]; k1 = hn[1][r]; }                   \
            h_prev[0][r] = k0; h_prev[1][r] = k1;                                               \
            s_h[buf ^ 1][slot * 264 + wv * 32 + n16] = f2bf(k0);                                \
            s_h[buf ^ 1][slot * 264 + wv * 32 + 16 + n16] = f2bf(k1);                           \
            if (alive) t_cur[r] = tn;                                                           \
        }                                                                                       \
        buf ^= 1;                                                                               \
    }

__launch_bounds__(512, 2)
__global__ void gru_scan(const unsigned short* __restrict__ GI, const int* __restrict__ resets,
                         const float* __restrict__ carry, const unsigned short* __restrict__ WhFrag,
                         const float* __restrict__ bhn, float* __restrict__ out) {
    __shared__ int s_reset[512];                         //   2,048 B
    __shared__ unsigned short s_h[2][16 * 264];          //  16,896 B (h bf16, A-operand, dbuf)
    __shared__ unsigned short s_whn[8 * 16 * 512];       // 131,072 B (n-gate Wh frags, per-wave)

    const int b = blockIdx.x;
    const int tid = threadIdx.x;
    const int lane = tid & 63, wv = tid >> 6;
    const int quad = lane >> 4, n16 = lane & 15;

    s_reset[tid] = resets[tid * 256 + b];

    // Wh fragments: r,z gates resident in VGPRs (32 frags = 128 regs); n gate -> LDS.
    const unsigned short* wfbase = WhFrag + (size_t)wv * 48 * 512 + lane * 8;
    bf16x8 wfr[4][8];
#pragma unroll
    for (int g2 = 0; g2 < 4; ++g2)
#pragma unroll
        for (int kt = 0; kt < 8; ++kt)
            wfr[g2][kt] = *(const bf16x8*)(wfbase + (g2 * 8 + kt) * 512);
#pragma unroll
    for (int j2 = 0; j2 < 16; ++j2) {
        bf16x8 v = *(const bf16x8*)(wfbase + (32 + j2) * 512);
        *(bf16x8*)(&s_whn[(wv * 16 + j2) * 512 + lane * 8]) = v;
    }
    float bhn_r[2];
    bhn_r[0] = bhn[wv * 32 + n16];
    bhn_r[1] = bhn[wv * 32 + 16 + n16];

    __syncthreads();   // s_reset visible to all

    // per-slot [start, end] from the reset pattern
    int t_cur[4], t_end[4];
    float h_prev[2][4];
#pragma unroll
    for (int r = 0; r < 4; ++r) {
        const int slot = quad * 4 + r;
        const int w0 = slot * 32;
        int st = -1;
        for (int t = w0; t < w0 + 32; ++t)
            if (t == 0 || s_reset[t] != 0) { st = t; break; }
        int en = 511;
        for (int t = w0 + 32; t < 512; ++t)
            if (s_reset[t] != 0) { en = t - 1; break; }
        float h0 = 0.f, h1 = 0.f;
        if (st == 0 && s_reset[0] == 0) {   // faithful: initial carry when t=0 not reset
            h0 = carry[b * 256 + wv * 32 + n16];
            h1 = carry[b * 256 + wv * 32 + 16 + n16];
        }
        if (st < 0) { t_cur[r] = 1; t_end[r] = 0; }   // dead slot (no segment starts here)
        else        { t_cur[r] = st; t_end[r] = en; }
        h_prev[0][r] = h0; h_prev[1][r] = h1;
        s_h[0][slot * 264 + wv * 32 + n16] = f2bf(h0);
        s_h[0][slot * 264 + wv * 32 + 16 + n16] = f2bf(h1);
    }

    // GI packed-uint base: lane reads uints {g*128 + wv*16 + n16} of row (b,t)
    const unsigned int* GI32 = (const unsigned int*)GI + (size_t)b * 512 * 384;
    const int gcol = wv * 16 + n16;
    unsigned int gva[4][3], gvb[4][3];
#pragma unroll
    for (int r = 0; r < 4; ++r) {
        const int tr0 = (t_cur[r] <= t_end[r]) ? t_cur[r] : 0;
        const unsigned int* gp = GI32 + (size_t)tr0 * 384 + gcol;
        gva[r][0] = gp[0]; gva[r][1] = gp[128]; gva[r][2] = gp[256];
    }

    int buf = 0;
    for (int it2 = 0; it2 < 256; ++it2) {
        SCAN_STEP(gva, gvb)
        SCAN_STEP(gvb, gva)
    }
}

// ---------------------------------------------------------------- launch
extern "C" void kernel_launch(void* const* d_in, const int* in_sizes, int n_in,
                              void* d_out, int out_size, void* d_ws, size_t ws_size,
                              hipStream_t stream) {
    const float* ins   = (const float*)d_in[0];
    const int* resets  = (const int*)d_in[1];
    const float* carry = (const float*)d_in[2];
    const float* Wi    = (const float*)d_in[3];
    const float* bi    = (const float*)d_in[4];
    const float* Wh    = (const float*)d_in[5];
    const float* bhn   = (const float*)d_in[6];
    float* out = (float*)d_out;

    unsigned short* WiT    = (unsigned short*)d_ws;     // [768][256] bf16
    unsigned short* WhFrag = WiT + 196608;              // [8][48][64][8] bf16 fragment-major
    unsigned short* GI     = WhFrag + 196608;           // [256][512][perm 768] bf16 (b-major)

    prep_weights<<<dim3(768, 2), dim3(256), 0, stream>>>(Wi, Wh, WiT, WhFrag);
    gi_gemm<<<dim3(6144), dim3(256), 0, stream>>>(ins, WiT, bi, GI);
    gru_scan<<<dim3(256), dim3(512), 0, stream>>>(GI, resets, carry, WhFrag, bhn, out);
}

// Round 3
// 429.163 us; speedup vs baseline: 1.3749x; 1.3316x over previous
//
#include <hip/hip_runtime.h>
#include <stdint.h>

// Problem constants (fixed by reference): T=512, B=256, H=256, 3H=768.
// Pipeline:
//   prep_weights: Wi,Wh (fp32 [256][768]) -> WiT,WhT (bf16 [768][256]).
//   gi_gemm:      R0 persistent structure: 256 blocks x 512 thr, Wi fragments
//                 register-resident, 32 chunks of 16 t-major rows (contiguous
//                 16-KB A loads). NEW: no f32 LDS epilogue -- acc (tl=0,1) pairs
//                 are cols (c,c+16), packed to one uint and stored directly to
//                 pair-permuted t-major GI (contiguous 24-KB chunk writes; fixes
//                 R1/R2's 2.5x write amplification from 256-B partial segments).
//   gru_scan:     reset-segment-parallel scan (R0 structure, 199us verified),
//                 all 48 Wh frags reg/AGPR-resident. NEW: T14 async-split GI
//                 staging -- speculative t+1 rows loaded to regs at iter top,
//                 written to s_gi[buf^1] after MFMA+gates (~700cy overlap; R0
//                 issued stage loads right before the barrier = full HBM latency
//                 exposed every iteration). Gates read GI as packed uints.
// GI layout: t-major, pair-permuted. uint index ((t*256+b)*384 + g*128 + w)
//   holds cols {lo: g*256+w*2 mapped (c=32*(w>>4)+ (w&15)), hi: c+16}, i.e.
//   lane (wv,n16) reads uint g*128+wv*16+n16 -> {c=wv*32+n16, c+16}.
// MFMA 16x16x32 bf16 layouts (HW-verified):
//   A[m=lane&15][k=quad*8+j], B[k=quad*8+j][n=lane&15], C/D[row=quad*4+reg][col=lane&15]

typedef __attribute__((ext_vector_type(8))) __bf16 bf16x8;
typedef __attribute__((ext_vector_type(4))) float f32x4;

__device__ __forceinline__ float bf2f(unsigned short u) {
    union { unsigned int i; float f; } v; v.i = ((unsigned int)u) << 16; return v.f;
}
__device__ __forceinline__ unsigned short f2bf(float f) {
    union { float f; unsigned int i; } v; v.f = f;
    unsigned int x = v.i;
    x = x + 0x7fffu + ((x >> 16) & 1u);   // RNE
    return (unsigned short)(x >> 16);
}
__device__ __forceinline__ float fsig(float x) {
    return __builtin_amdgcn_rcpf(1.f + __builtin_amdgcn_exp2f(-1.442695041f * x));
}
__device__ __forceinline__ float ftanh(float x) {
    return 1.f - 2.f * __builtin_amdgcn_rcpf(1.f + __builtin_amdgcn_exp2f(2.885390082f * x));
}

// ---------------------------------------------------------------- prep
__global__ void prep_weights(const float* __restrict__ Wi, const float* __restrict__ Wh,
                             unsigned short* __restrict__ WiT, unsigned short* __restrict__ WhT) {
    const int idx = blockIdx.x * 256 + threadIdx.x;          // [0, 196608)
    const float* src = blockIdx.y ? Wh : Wi;
    unsigned short* dst = blockIdx.y ? WhT : WiT;
    const int c = idx >> 8, k = idx & 255;
    dst[c * 256 + k] = f2bf(src[k * 768 + c]);
}

// ---------------------------------------------------------------- kernel 1: GI = ins@Wi + bi
__launch_bounds__(512, 2)
__global__ void gi_gemm(const float* __restrict__ ins, const unsigned short* __restrict__ WiT,
                        const float* __restrict__ bi, unsigned int* __restrict__ GI32) {
    __shared__ unsigned short a_buf[2][16 * 264];   // dbuf: 16 rows x (256+8) bf16

    const int tid = threadIdx.x;
    const int lane = tid & 63, wv = tid >> 6;       // 8 waves
    const int quad = lane >> 4, n16 = lane & 15;

    // Wi B-fragments: wave owns hidden cols [32wv,32wv+32) of each gate (r,z,n)
    bf16x8 wfrag[3][2][8];
#pragma unroll
    for (int g = 0; g < 3; ++g)
#pragma unroll
        for (int tl = 0; tl < 2; ++tl) {
            const int c = g * 256 + wv * 32 + tl * 16 + n16;
            const unsigned short* src = WiT + c * 256 + quad * 8;
#pragma unroll
            for (int kt = 0; kt < 8; ++kt)
                wfrag[g][tl][kt] = *(const bf16x8*)(src + kt * 32);
        }
    float bi_r[3][2];
#pragma unroll
    for (int g = 0; g < 3; ++g)
#pragma unroll
        for (int tl = 0; tl < 2; ++tl)
            bi_r[g][tl] = bi[g * 256 + wv * 32 + tl * 16 + n16];

    const int srow = tid >> 5;        // staging row 0..15
    const int scol = (tid & 31) * 8;  // staging col

    float4 p0, p1;
    {
        const float* p = ins + (size_t)blockIdx.x * 16 * 256 + tid * 8;
        p0 = *(const float4*)p; p1 = *(const float4*)(p + 4);
    }

    int buf = 0;
    for (int i = 0; i < 32; ++i) {
        const int chunk = blockIdx.x + i * 256;  // 16 consecutive t-major rows
        // stage current chunk (prefetched) into LDS as bf16
        {
            bf16x8 av;
            av[0] = (__bf16)p0.x; av[1] = (__bf16)p0.y; av[2] = (__bf16)p0.z; av[3] = (__bf16)p0.w;
            av[4] = (__bf16)p1.x; av[5] = (__bf16)p1.y; av[6] = (__bf16)p1.z; av[7] = (__bf16)p1.w;
            *(bf16x8*)(&a_buf[buf][srow * 264 + scol]) = av;
        }
        if (i + 1 < 32) {  // prefetch next chunk (contiguous 16 KB / block)
            const float* p = ins + (size_t)(blockIdx.x + (i + 1) * 256) * 16 * 256 + tid * 8;
            p0 = *(const float4*)p; p1 = *(const float4*)(p + 4);
        }
        __syncthreads();   // single barrier per chunk (a_buf double-buffered)

        f32x4 acc[3][2] = {};
#pragma unroll
        for (int kt = 0; kt < 8; ++kt) {
            bf16x8 af = *(const bf16x8*)(&a_buf[buf][n16 * 264 + kt * 32 + quad * 8]);
#pragma unroll
            for (int g = 0; g < 3; ++g)
#pragma unroll
                for (int tl = 0; tl < 2; ++tl)
                    acc[g][tl] = __builtin_amdgcn_mfma_f32_16x16x32_bf16(af, wfrag[g][tl][kt], acc[g][tl], 0, 0, 0);
        }
        // direct packed epilogue: row = t*256 + b0 + quad*4 + r (chunk rows are
        // 16 consecutive b at fixed t) -> 24 KB contiguous per chunk, full lines.
        {
            const int t = chunk >> 4;
            const int b0 = (chunk & 15) * 16;
#pragma unroll
            for (int g = 0; g < 3; ++g)
#pragma unroll
                for (int r = 0; r < 4; ++r) {
                    const unsigned int lo = f2bf(acc[g][0][r] + bi_r[g][0]);
                    const unsigned int hi = f2bf(acc[g][1][r] + bi_r[g][1]);
                    GI32[((size_t)t * 256 + b0 + quad * 4 + r) * 384 + g * 128 + wv * 16 + n16] =
                        lo | (hi << 16);
                }
        }
        buf ^= 1;
    }
}

// ---------------------------------------------------------------- kernel 2: segment-parallel GRU scan
// slot = quad*4+r owns window [slot*32, slot*32+32): processes rows [start,end]
// consecutively. GI rows staged to LDS with T14 async-split (speculative t+1).
__launch_bounds__(512, 2)
__global__ void gru_scan(const unsigned short* __restrict__ GI, const int* __restrict__ resets,
                         const float* __restrict__ carry, const unsigned short* __restrict__ WhT,
                         const float* __restrict__ bhn, float* __restrict__ out) {
    __shared__ int s_reset[512];                    //  2,048 B
    __shared__ unsigned short s_h[2][16 * 264];     // 16,896 B (h bf16, A-operand, dbuf)
    __shared__ unsigned int s_gi[2][16 * 386];      // 49,408 B (gi rows, packed uints, dbuf;
                                                    //  stride 386: quad*1544B = +8 banks -> <=2-way)
    const int b = blockIdx.x;
    const int tid = threadIdx.x;
    const int lane = tid & 63, wv = tid >> 6;
    const int quad = lane >> 4, n16 = lane & 15;

    s_reset[tid] = resets[tid * 256 + b];

    // Wh B-fragments (register/AGPR-resident for the whole scan; R0-verified)
    bf16x8 wfrag[3][2][8];
#pragma unroll
    for (int g = 0; g < 3; ++g)
#pragma unroll
        for (int tl = 0; tl < 2; ++tl) {
            const int c = g * 256 + wv * 32 + tl * 16 + n16;
            const unsigned short* src = WhT + c * 256 + quad * 8;
#pragma unroll
            for (int kt = 0; kt < 8; ++kt)
                wfrag[g][tl][kt] = *(const bf16x8*)(src + kt * 32);
        }
    float bhn_r[2];
    bhn_r[0] = bhn[wv * 32 + n16];
    bhn_r[1] = bhn[wv * 32 + 16 + n16];

    __syncthreads();   // s_reset visible

    // per-slot [start, end] from the reset pattern (R2-verified logic)
    int t_cur[4], t_end[4];
    float h_prev[2][4];
#pragma unroll
    for (int r = 0; r < 4; ++r) {
        const int slot = quad * 4 + r;
        const int w0 = slot * 32;
        int st = -1;
        for (int t = w0; t < w0 + 32; ++t)
            if (t == 0 || s_reset[t] != 0) { st = t; break; }
        int en = 511;
        for (int t = w0 + 32; t < 512; ++t)
            if (s_reset[t] != 0) { en = t - 1; break; }
        float h0 = 0.f, h1 = 0.f;
        if (st == 0 && s_reset[0] == 0) {   // faithful: initial carry when t=0 not reset
            h0 = carry[b * 256 + wv * 32 + n16];
            h1 = carry[b * 256 + wv * 32 + 16 + n16];
        }
        if (st < 0) { t_cur[r] = 1; t_end[r] = 0; }   // dead slot
        else        { t_cur[r] = st; t_end[r] = en; }
        h_prev[0][r] = h0; h_prev[1][r] = h1;
        s_h[0][slot * 264 + wv * 32 + n16] = f2bf(h0);
        s_h[0][slot * 264 + wv * 32 + 16 + n16] = f2bf(h1);
    }

    const int srcl = (wv >> 1) * 16;   // lane whose quad tracks this wave's 2 slots
    const unsigned short* gbase = GI + (size_t)b * 768;

    // prologue: stage iteration-0 rows into s_gi[0]
    {
        int c0 = (t_cur[0] <= t_end[0]) ? t_cur[0] : 0;
        int c1 = (t_cur[1] <= t_end[1]) ? t_cur[1] : 0;
        int c2 = (t_cur[2] <= t_end[2]) ? t_cur[2] : 0;
        int c3 = (t_cur[3] <= t_end[3]) ? t_cur[3] : 0;
        const int v0 = __builtin_amdgcn_readlane(c0, srcl);
        const int v1 = __builtin_amdgcn_readlane(c1, srcl);
        const int v2 = __builtin_amdgcn_readlane(c2, srcl);
        const int v3 = __builtin_amdgcn_readlane(c3, srcl);
        const int r0 = (wv & 1) ? v2 : v0;
        const int r1 = (wv & 1) ? v3 : v1;
        const uint2* s0 = (const uint2*)(gbase + (size_t)r0 * 196608) + lane * 3;
        const uint2* s1 = (const uint2*)(gbase + (size_t)r1 * 196608) + lane * 3;
        uint2* d0 = (uint2*)(&s_gi[0][(2 * wv) * 386]) + lane * 3;
        uint2* d1 = (uint2*)(&s_gi[0][(2 * wv + 1) * 386]) + lane * 3;
        d0[0] = s0[0]; d0[1] = s0[1]; d0[2] = s0[2];
        d1[0] = s1[0]; d1[1] = s1[1]; d1[2] = s1[2];
    }
    __syncthreads();

    int buf = 0;
    for (int it = 0; it < 520; ++it) {
        const bool any = (t_cur[0] <= t_end[0]) | (t_cur[1] <= t_end[1]) |
                         (t_cur[2] <= t_end[2]) | (t_cur[3] <= t_end[3]);
        if (__ballot((int)any) == 0ull) break;   // uniform: all waves track all 16 slots

        // A) speculative prefetch of next-iteration rows (t+1) -> registers
        uint2 pf0a, pf0b, pf0c, pf1a, pf1b, pf1c;
        {
            int s0_ = (t_cur[0] < t_end[0]) ? t_cur[0] + 1 : 0;
            int s1_ = (t_cur[1] < t_end[1]) ? t_cur[1] + 1 : 0;
            int s2_ = (t_cur[2] < t_end[2]) ? t_cur[2] + 1 : 0;
            int s3_ = (t_cur[3] < t_end[3]) ? t_cur[3] + 1 : 0;
            const int v0 = __builtin_amdgcn_readlane(s0_, srcl);
            const int v1 = __builtin_amdgcn_readlane(s1_, srcl);
            const int v2 = __builtin_amdgcn_readlane(s2_, srcl);
            const int v3 = __builtin_amdgcn_readlane(s3_, srcl);
            const int r0 = (wv & 1) ? v2 : v0;
            const int r1 = (wv & 1) ? v3 : v1;
            const uint2* s0 = (const uint2*)(gbase + (size_t)r0 * 196608) + lane * 3;
            const uint2* s1 = (const uint2*)(gbase + (size_t)r1 * 196608) + lane * 3;
            pf0a = s0[0]; pf0b = s0[1]; pf0c = s0[2];
            pf1a = s1[0]; pf1b = s1[1]; pf1c = s1[2];
        }

        // B) gh = h @ Wh for all 16 slots (overlaps the prefetch latency)
        f32x4 acc2[3][2] = {};
#pragma unroll
        for (int kt = 0; kt < 8; ++kt) {
            bf16x8 af = *(const bf16x8*)(&s_h[buf][n16 * 264 + kt * 32 + quad * 8]);
#pragma unroll
            for (int g = 0; g < 3; ++g)
#pragma unroll
                for (int tl = 0; tl < 2; ++tl)
                    acc2[g][tl] = __builtin_amdgcn_mfma_f32_16x16x32_bf16(af, wfrag[g][tl][kt], acc2[g][tl], 0, 0, 0);
        }

        // C) gates + h update + output
        float hn[2][4];
#pragma unroll
        for (int r = 0; r < 4; ++r) {
            const bool alive = t_cur[r] <= t_end[r];
            const unsigned int* gp = &s_gi[buf][(quad * 4 + r) * 386 + wv * 16 + n16];
            const unsigned int ur = gp[0], uz = gp[128], un = gp[256];
#pragma unroll
            for (int tl = 0; tl < 2; ++tl) {
                const int c = wv * 32 + tl * 16 + n16;
                const float gr = bf2f((unsigned short)(tl ? (ur >> 16) : (ur & 0xffffu)));
                const float gz = bf2f((unsigned short)(tl ? (uz >> 16) : (uz & 0xffffu)));
                const float gn = bf2f((unsigned short)(tl ? (un >> 16) : (un & 0xffffu)));
                const float rr = fsig(gr + acc2[0][tl][r]);
                const float zz = fsig(gz + acc2[1][tl][r]);
                const float nn = ftanh(gn + rr * (acc2[2][tl][r] + bhn_r[tl]));
                hn[tl][r] = (1.f - zz) * nn + zz * h_prev[tl][r];
                if (alive) out[((size_t)t_cur[r] * 256 + b) * 256 + c] = hn[tl][r];
            }
        }

        // D) advance + write h for next iteration
#pragma unroll
        for (int r = 0; r < 4; ++r) {
            const int slot = quad * 4 + r;
            const bool alive = t_cur[r] <= t_end[r];
            const int tn = t_cur[r] + 1;
            const bool nalive = alive && (tn <= t_end[r]);
            float k0 = 0.f, k1 = 0.f;
            if (nalive && s_reset[tn & 511] == 0) { k0 = hn[0][r]; k1 = hn[1][r]; }
            h_prev[0][r] = k0; h_prev[1][r] = k1;
            s_h[buf ^ 1][slot * 264 + wv * 32 + n16] = f2bf(k0);
            s_h[buf ^ 1][slot * 264 + wv * 32 + 16 + n16] = f2bf(k1);
            if (alive) t_cur[r] = tn;
        }

        // E) drain prefetch regs -> s_gi[buf^1] (vmcnt wait covered by B+C+D)
        {
            uint2* d0 = (uint2*)(&s_gi[buf ^ 1][(2 * wv) * 386]) + lane * 3;
            uint2* d1 = (uint2*)(&s_gi[buf ^ 1][(2 * wv + 1) * 386]) + lane * 3;
            d0[0] = pf0a; d0[1] = pf0b; d0[2] = pf0c;
            d1[0] = pf1a; d1[1] = pf1b; d1[2] = pf1c;
        }
        __syncthreads();   // single barrier per iteration
        buf ^= 1;
    }
}

// ---------------------------------------------------------------- launch
extern "C" void kernel_launch(void* const* d_in, const int* in_sizes, int n_in,
                              void* d_out, int out_size, void* d_ws, size_t ws_size,
                              hipStream_t stream) {
    const float* ins   = (const float*)d_in[0];
    const int* resets  = (const int*)d_in[1];
    const float* carry = (const float*)d_in[2];
    const float* Wi    = (const float*)d_in[3];
    const float* bi    = (const float*)d_in[4];
    const float* Wh    = (const float*)d_in[5];
    const float* bhn   = (const float*)d_in[6];
    float* out = (float*)d_out;

    unsigned short* WiT = (unsigned short*)d_ws;        // [768][256] bf16
    unsigned short* WhT = WiT + 196608;                 // [768][256] bf16
    unsigned short* GI  = WhT + 196608;                 // [512][256][perm 768] bf16 (t-major, packed pairs)

    prep_weights<<<dim3(768, 2), dim3(256), 0, stream>>>(Wi, Wh, WiT, WhT);
    gi_gemm<<<dim3(256), dim3(512), 0, stream>>>(ins, WiT, bi, (unsigned int*)GI);
    gru_scan<<<dim3(256), dim3(512), 0, stream>>>(GI, resets, carry, WhT, bhn, out);
}